// Round 7
// baseline (819.414 us; speedup 1.0000x reference)
//
#include <hip/hip_runtime.h>
#include <math.h>

// Problem constants
#define B_   128
#define E_   512
#define H_   512
#define S_   2048
#define V_   83
#define PAD_ 82

typedef float v4f __attribute__((ext_vector_type(4)));

__device__ __forceinline__ v4f ldnt4(const float* p) {
    return __builtin_nontemporal_load((const v4f*)p);
}

// ---- one-time prep -------------------------------------------------------

// pe2[e] = pe(e,2); x01i[e*3+{0,1,2}] = {embPAD[e]+pe(e,0), embPAD[e]+pe(e,1), 0}
__global__ void k_misc(const float* __restrict__ emb, float* __restrict__ pe2,
                       float* __restrict__ x01i) {
    int e = threadIdx.x;                              // 1 block, 512 threads
    float freq = expf(-9.210340371976184f * (float)(e & ~1) * (1.0f / 512.0f));
    float p0 = (e & 1) ? 1.0f : 0.0f;                 // cos(0)/sin(0)
    float p1 = (e & 1) ? cosf(freq) : sinf(freq);
    float p2 = (e & 1) ? cosf(2.0f * freq) : sinf(2.0f * freq);
    pe2[e] = p2;
    float ep = emb[PAD_ * 512 + e];
    x01i[e * 3 + 0] = ep + p0;
    x01i[e * 3 + 1] = ep + p1;
    x01i[e * 3 + 2] = 0.0f;
}

// base[o] = dot(conv_w[o, 0:1536], x01i)  — contiguous row reads, wave per o
__global__ void k_base3(const float* __restrict__ cw, const float* __restrict__ x01i,
                        float* __restrict__ base) {
    int t = threadIdx.x, w = t >> 6, lane = t & 63;   // grid 256, block 256
    __shared__ float xs[1536];
    for (int j = t; j < 1536; j += 256) xs[j] = x01i[j];
    __syncthreads();
    int o = blockIdx.x * 4 + w;
    const float* rp = cw + (size_t)o * 1536 + lane * 4;
    float acc = 0.f;
    #pragma unroll
    for (int j = 0; j < 6; ++j) {
        float4 v = *(const float4*)(rp + j * 256);
        const float* xp = &xs[lane * 4 + j * 256];
        acc += v.x * xp[0] + v.y * xp[1] + v.z * xp[2] + v.w * xp[3];
    }
    #pragma unroll
    for (int off = 32; off > 0; off >>= 1) acc += __shfl_down(acc, off, 64);
    if (lane == 0) base[o] = acc;
}

// LDS-tiled transpose: W2t[e*1024 + o] = conv_w[o*1536 + e*3 + 2]
__global__ void k_prep(const float* __restrict__ cw, float* __restrict__ W2t) {
    __shared__ float tile[64][129];                   // +1 pad
    int ob = blockIdx.x * 64, eb = blockIdx.y * 128;
    int t = threadIdx.x;                              // block 256
    for (int idx = t; idx < 8192; idx += 256) {
        int r = idx >> 7, e = idx & 127;
        tile[r][e] = cw[(size_t)(ob + r) * 1536 + (eb + e) * 3 + 2];
    }
    __syncthreads();
    for (int idx = t; idx < 8192; idx += 256) {
        int e = idx >> 6, o = idx & 63;
        W2t[(size_t)(eb + e) * 1024 + ob + o] = tile[o][e];
    }
}

// ---- per-layer kernels ---------------------------------------------------

// fused k_x + k_y (R5-proven): xs[4][512] = src + pe2 (oc==0 writes xcol),
// y[b,o] = base[o]+cb[o]+sum_e xs[b][e]*W2t[e,o]
__global__ void k_yx(int first, const int* __restrict__ tok, const float* __restrict__ emb,
                     const float* __restrict__ h, const float* __restrict__ pe2,
                     const float* __restrict__ W2t, const float* __restrict__ base,
                     const float* __restrict__ cb, float* __restrict__ xcol,
                     float* __restrict__ y) {
    int oc = blockIdx.x, bq = blockIdx.y, t = threadIdx.x;  // grid (4,32), block 256
    __shared__ float xs[4][512];
    for (int j = t; j < 2048; j += 256) {
        int bb = j >> 9, e = j & 511;
        int b = bq * 4 + bb;
        float v = first ? emb[tok[b] * 512 + e] : h[b * 512 + e];
        xs[bb][e] = v + pe2[e];
    }
    __syncthreads();
    if (oc == 0)
        for (int j = t; j < 2048; j += 256) xcol[bq * 2048 + j] = xs[j >> 9][j & 511];
    int o = oc * 256 + t;
    float init = base[o] + cb[o];
    float a0 = init, a1 = init, a2 = init, a3 = init;
    for (int e = 0; e < 512; ++e) {
        float w = W2t[e * 1024 + o];
        a0 += xs[0][e] * w; a1 += xs[1][e] * w;
        a2 += xs[2][e] * w; a3 += xs[3][e] * w;
    }
    int b0 = bq * 4;
    y[(size_t)(b0 + 0) * 1024 + o] = a0;
    y[(size_t)(b0 + 1) * 1024 + o] = a1;
    y[(size_t)(b0 + 2) * 1024 + o] = a2;
    y[(size_t)(b0 + 3) * 1024 + o] = a3;
}

// Fused flash-style attention over one s-chunk of 512:
// grid (4 sc, 128 b), block 256 = 4 waves.
// Phase A: d[512] from y/xcol.  Phase B: partial scores for local s (wave w = h-rows
// w*128..+128, lane owns 8 consecutive s).  Phase C: local softmax (M, l, p).
// Phase D: partial c_h = sum_{s local} p_s * enc_tot[b,h,s].
__global__ void k_attn(const float* __restrict__ y, const float* __restrict__ xcol,
                       const float* __restrict__ eo, const float* __restrict__ et,
                       float* __restrict__ partC, float* __restrict__ partML) {
    int sc = blockIdx.x, b = blockIdx.y, t = threadIdx.x;
    int w = t >> 6, lane = t & 63;
    __shared__ float dl[512];
    __shared__ float red[4][512];
    __shared__ float p[512];
    __shared__ float r[256];
    for (int j = t; j < 512; j += 256) {
        float ya = y[b * 1024 + j], yb_ = y[b * 1024 + 512 + j];
        float g = ya / (1.0f + expf(-yb_));
        dl[j] = g + xcol[b * 512 + j];
    }
    __syncthreads();
    // Phase B: scores
    v4f a0 = (v4f)(0.f), a1 = (v4f)(0.f);
    const float* bp = eo + ((size_t)b * 512 + w * 128) * 2048 + sc * 512 + lane * 8;
    for (int rr = 0; rr < 128; ++rr) {
        float dh = dl[w * 128 + rr];
        const float* rp = bp + (size_t)rr * 2048;
        a0 += dh * ldnt4(rp);
        a1 += dh * ldnt4(rp + 4);
    }
    *(v4f*)&red[w][lane * 8] = a0;
    *(v4f*)&red[w][lane * 8 + 4] = a1;
    __syncthreads();
    // Phase C: combine waves + local softmax over the 512 chunk scores
    float s0 = red[0][t] + red[1][t] + red[2][t] + red[3][t];
    float s1 = red[0][t + 256] + red[1][t + 256] + red[2][t + 256] + red[3][t + 256];
    r[t] = fmaxf(s0, s1); __syncthreads();
    for (int st = 128; st > 0; st >>= 1) { if (t < st) r[t] = fmaxf(r[t], r[t + st]); __syncthreads(); }
    float M = r[0]; __syncthreads();
    float e0 = expf(s0 - M), e1 = expf(s1 - M);
    p[t] = e0; p[t + 256] = e1;
    r[t] = e0 + e1; __syncthreads();
    for (int st = 128; st > 0; st >>= 1) { if (t < st) r[t] += r[t + st]; __syncthreads(); }
    if (t == 0) { partML[(b * 4 + sc) * 2 + 0] = M; partML[(b * 4 + sc) * 2 + 1] = r[0]; }
    __syncthreads();
    // Phase D: partial context (unnormalized, scaled by e^-M)
    const float* vp = et + ((size_t)b * 512 + w * 128) * 2048 + sc * 512 + lane * 8;
    v4f pp0 = *(const v4f*)&p[lane * 8];
    v4f pp1 = *(const v4f*)&p[lane * 8 + 4];
    float* pc = partC + ((size_t)(b * 4 + sc)) * 512 + w * 128;
    for (int rr = 0; rr < 128; ++rr) {
        const float* rp = vp + (size_t)rr * 2048;
        v4f m0 = pp0 * ldnt4(rp) + pp1 * ldnt4(rp + 4);
        float acc = (m0[0] + m0[1]) + (m0[2] + m0[3]);
        #pragma unroll
        for (int off = 32; off > 0; off >>= 1) acc += __shfl_down(acc, off, 64);
        if (lane == 0) pc[rr] = acc;
    }
}

// Merge 4 chunk-partials (logsumexp weights), add glu(y) -> hbuf.  grid 128, block 512.
__global__ void k_comb(const float* __restrict__ partC, const float* __restrict__ partML,
                       const float* __restrict__ y, float* __restrict__ hbuf) {
    int b = blockIdx.x, t = threadIdx.x;
    float m0 = partML[(b * 4 + 0) * 2], l0 = partML[(b * 4 + 0) * 2 + 1];
    float m1 = partML[(b * 4 + 1) * 2], l1 = partML[(b * 4 + 1) * 2 + 1];
    float m2 = partML[(b * 4 + 2) * 2], l2 = partML[(b * 4 + 2) * 2 + 1];
    float m3 = partML[(b * 4 + 3) * 2], l3 = partML[(b * 4 + 3) * 2 + 1];
    float M = fmaxf(fmaxf(m0, m1), fmaxf(m2, m3));
    float w0 = expf(m0 - M), w1 = expf(m1 - M), w2 = expf(m2 - M), w3 = expf(m3 - M);
    float Z = w0 * l0 + w1 * l1 + w2 * l2 + w3 * l3;
    float c = (w0 * partC[(size_t)(b * 4 + 0) * 512 + t] +
               w1 * partC[(size_t)(b * 4 + 1) * 512 + t] +
               w2 * partC[(size_t)(b * 4 + 2) * 512 + t] +
               w3 * partC[(size_t)(b * 4 + 3) * 512 + t]) / Z;
    float ya = y[b * 1024 + t], yb_ = y[b * 1024 + 512 + t];
    float g = ya / (1.0f + expf(-yb_));
    hbuf[b * 512 + t] = g + c;
}

// ---- epilogue (fused logits/log-softmax + softmax over H) ---------------

__global__ void k_epi(const float* __restrict__ h, const float* __restrict__ l2w,
                      const float* __restrict__ l2b, float* __restrict__ out) {
    int b = blockIdx.x, t = threadIdx.x;              // block 256
    __shared__ float hl[512];
    hl[t] = h[b * 512 + t]; hl[t + 256] = h[b * 512 + 256 + t];
    __syncthreads();
    float acc = 0.f;
    if (t < V_) {
        acc = l2b[t];
        for (int e = 0; e < 512; ++e) acc += hl[e] * l2w[t * 512 + e];
    }
    __shared__ float r[256];
    r[t] = (t < V_) ? acc : -1e30f; __syncthreads();
    for (int s = 128; s > 0; s >>= 1) { if (t < s) r[t] = fmaxf(r[t], r[t + s]); __syncthreads(); }
    float M = r[0]; __syncthreads();
    r[t] = (t < V_) ? expf(acc - M) : 0.f; __syncthreads();
    for (int s = 128; s > 0; s >>= 1) { if (t < s) r[t] += r[t + s]; __syncthreads(); }
    float L = M + logf(r[0]);
    if (t < V_) out[65536 + b * V_ + t] = acc - L;
    __syncthreads();
    float v0 = hl[t], v1 = hl[t + 256];
    r[t] = fmaxf(v0, v1); __syncthreads();
    for (int s = 128; s > 0; s >>= 1) { if (t < s) r[t] = fmaxf(r[t], r[t + s]); __syncthreads(); }
    float M2 = r[0]; __syncthreads();
    float e0 = expf(v0 - M2), e1 = expf(v1 - M2);
    r[t] = e0 + e1; __syncthreads();
    for (int s = 128; s > 0; s >>= 1) { if (t < s) r[t] += r[t + s]; __syncthreads(); }
    float inv = 1.0f / r[0];
    out[b * 512 + t] = e0 * inv;
    out[b * 512 + 256 + t] = e1 * inv;
}

// ---- launch --------------------------------------------------------------

extern "C" void kernel_launch(void* const* d_in, const int* in_sizes, int n_in,
                              void* d_out, int out_size, void* d_ws, size_t ws_size,
                              hipStream_t stream) {
    const float* enc_out = (const float*)d_in[0];   // [B,H,S] f32
    const float* enc_tot = (const float*)d_in[1];   // [B,H,S] f32
    const int*   tok     = (const int*)d_in[2];     // [B] int32
    const float* emb     = (const float*)d_in[4];   // [V,E] f32
    const float* conv_w  = (const float*)d_in[5];   // [1024,512,3] f32
    const float* conv_b  = (const float*)d_in[6];   // [1024] f32
    const float* l2w     = (const float*)d_in[7];   // [83,512] f32
    const float* l2b     = (const float*)d_in[8];   // [83] f32
    float* out = (float*)d_out;                     // 65536 + 10624 f32
    float* ws = (float*)d_ws;

    // ws layout (floats)
    float* W2t   = ws;                 // 524288
    float* base  = W2t + 524288;       // 1024
    float* pe2   = base + 1024;        // 512
    float* x01i  = pe2 + 512;          // 1536
    float* xcol  = x01i + 1536;        // 65536
    float* yb    = xcol + 65536;       // 131072
    float* hbuf  = yb + 131072;        // 65536
    float* partC = hbuf + 65536;       // 262144 (128*4*512)
    float* partML= partC + 262144;     // 1024
    // total ~4.2 MB

    k_misc<<<1, 512, 0, stream>>>(emb, pe2, x01i);
    k_base3<<<256, 256, 0, stream>>>(conv_w, x01i, base);
    k_prep<<<dim3(16, 4), 256, 0, stream>>>(conv_w, W2t);

    for (int L = 0; L < 3; ++L) {
        k_yx<<<dim3(4, 32), 256, 0, stream>>>(L == 0 ? 1 : 0, tok, emb, hbuf, pe2,
                                              W2t, base, conv_b, xcol, yb);
        k_attn<<<dim3(4, 128), 256, 0, stream>>>(yb, xcol, enc_out, enc_tot, partC, partML);
        k_comb<<<128, 512, 0, stream>>>(partC, partML, yb, hbuf);
    }

    k_epi<<<128, 256, 0, stream>>>(hbuf, l2w, l2b, out);
}

// Round 8
// 631.656 us; speedup vs baseline: 1.2972x; 1.2972x over previous
//
#include <hip/hip_runtime.h>
#include <math.h>

// Problem constants
#define B_   128
#define E_   512
#define H_   512
#define S_   2048
#define V_   83
#define PAD_ 82

typedef float v4f __attribute__((ext_vector_type(4)));
typedef _Float16 h4 __attribute__((ext_vector_type(4)));
typedef _Float16 h8 __attribute__((ext_vector_type(8)));

__device__ __forceinline__ v4f ldnt4(const float* p) {
    return __builtin_nontemporal_load((const v4f*)p);
}

// ---- one-time prep -------------------------------------------------------

// pe2[e] = pe(e,2); x01i[e*3+{0,1,2}] = {embPAD[e]+pe(e,0), embPAD[e]+pe(e,1), 0}
__global__ void k_misc(const float* __restrict__ emb, float* __restrict__ pe2,
                       float* __restrict__ x01i) {
    int e = threadIdx.x;                              // 1 block, 512 threads
    float freq = expf(-9.210340371976184f * (float)(e & ~1) * (1.0f / 512.0f));
    float p0 = (e & 1) ? 1.0f : 0.0f;                 // cos(0)/sin(0)
    float p1 = (e & 1) ? cosf(freq) : sinf(freq);
    float p2 = (e & 1) ? cosf(2.0f * freq) : sinf(2.0f * freq);
    pe2[e] = p2;
    float ep = emb[PAD_ * 512 + e];
    x01i[e * 3 + 0] = ep + p0;
    x01i[e * 3 + 1] = ep + p1;
    x01i[e * 3 + 2] = 0.0f;
}

// base[o] = dot(conv_w[o, 0:1536], x01i)  — contiguous row reads, wave per o
__global__ void k_base3(const float* __restrict__ cw, const float* __restrict__ x01i,
                        float* __restrict__ base) {
    int t = threadIdx.x, w = t >> 6, lane = t & 63;   // grid 256, block 256
    __shared__ float xs[1536];
    for (int j = t; j < 1536; j += 256) xs[j] = x01i[j];
    __syncthreads();
    int o = blockIdx.x * 4 + w;
    const float* rp = cw + (size_t)o * 1536 + lane * 4;
    float acc = 0.f;
    #pragma unroll
    for (int j = 0; j < 6; ++j) {
        float4 v = *(const float4*)(rp + j * 256);
        const float* xp = &xs[lane * 4 + j * 256];
        acc += v.x * xp[0] + v.y * xp[1] + v.z * xp[2] + v.w * xp[3];
    }
    #pragma unroll
    for (int off = 32; off > 0; off >>= 1) acc += __shfl_down(acc, off, 64);
    if (lane == 0) base[o] = acc;
}

// LDS-tiled transpose: W2t[e*1024 + o] = conv_w[o*1536 + e*3 + 2]
__global__ void k_prep(const float* __restrict__ cw, float* __restrict__ W2t) {
    __shared__ float tile[64][129];                   // +1 pad
    int ob = blockIdx.x * 64, eb = blockIdx.y * 128;
    int t = threadIdx.x;                              // block 256
    for (int idx = t; idx < 8192; idx += 256) {
        int r = idx >> 7, e = idx & 127;
        tile[r][e] = cw[(size_t)(ob + r) * 1536 + (eb + e) * 3 + 2];
    }
    __syncthreads();
    for (int idx = t; idx < 8192; idx += 256) {
        int e = idx >> 6, o = idx & 63;
        W2t[(size_t)(eb + e) * 1024 + ob + o] = tile[o][e];
    }
}

// ---- per-layer kernels ---------------------------------------------------

// fused k_x + k_y: xs[4][512] = src + pe2 (oc==0 writes xcol),
// y[b,o] = base[o]+cb[o]+sum_e xs[b][e]*W2t[e,o]
__global__ void k_yx(int first, const int* __restrict__ tok, const float* __restrict__ emb,
                     const float* __restrict__ h, const float* __restrict__ pe2,
                     const float* __restrict__ W2t, const float* __restrict__ base,
                     const float* __restrict__ cb, float* __restrict__ xcol,
                     float* __restrict__ y) {
    int oc = blockIdx.x, bq = blockIdx.y, t = threadIdx.x;  // grid (4,32), block 256
    __shared__ float xs[4][512];
    for (int j = t; j < 2048; j += 256) {
        int bb = j >> 9, e = j & 511;
        int b = bq * 4 + bb;
        float v = first ? emb[tok[b] * 512 + e] : h[b * 512 + e];
        xs[bb][e] = v + pe2[e];
    }
    __syncthreads();
    if (oc == 0)
        for (int j = t; j < 2048; j += 256) xcol[bq * 2048 + j] = xs[j >> 9][j & 511];
    int o = oc * 256 + t;
    float init = base[o] + cb[o];
    float a0 = init, a1 = init, a2 = init, a3 = init;
    for (int e = 0; e < 512; ++e) {
        float w = W2t[e * 1024 + o];
        a0 += xs[0][e] * w; a1 += xs[1][e] * w;
        a2 += xs[2][e] * w; a3 += xs[3][e] * w;
    }
    int b0 = bq * 4;
    y[(size_t)(b0 + 0) * 1024 + o] = a0;
    y[(size_t)(b0 + 1) * 1024 + o] = a1;
    y[(size_t)(b0 + 2) * 1024 + o] = a2;
    y[(size_t)(b0 + 3) * 1024 + o] = a3;
}

// partial scores: grid (8 hc, 128 b), block 256 = 4 waves; nt row streams.
__global__ void k_scores2(const float* __restrict__ y, const float* __restrict__ xcol,
                          const float* __restrict__ enc, float* __restrict__ part) {
    int hc = blockIdx.x, b = blockIdx.y, t = threadIdx.x;
    int w = t >> 6, lane = t & 63;
    __shared__ float dl[64];
    __shared__ float red[4 * 2048];
    if (t < 64) {
        int hg = hc * 64 + t;
        float ya = y[b * 1024 + hg];
        float yb_ = y[b * 1024 + 512 + hg];
        float g = ya / (1.0f + expf(-yb_));
        dl[t] = g + xcol[b * 512 + hg];
    }
    __syncthreads();
    v4f a[8];
    #pragma unroll
    for (int j = 0; j < 8; ++j) a[j] = (v4f)(0.f);
    const float* bp = enc + ((size_t)b * 512 + hc * 64 + w * 16) * 2048 + lane * 4;
    for (int r = 0; r < 16; ++r) {
        float dh = dl[w * 16 + r];
        const float* rp = bp + (size_t)r * 2048;
        #pragma unroll
        for (int j = 0; j < 8; ++j) {
            v4f v = ldnt4(rp + j * 256);
            a[j] += dh * v;
        }
    }
    #pragma unroll
    for (int j = 0; j < 8; ++j)
        *(v4f*)&red[w * 2048 + j * 256 + lane * 4] = a[j];
    __syncthreads();
    #pragma unroll
    for (int k = 0; k < 2; ++k) {
        int s = t * 4 + k * 1024;
        v4f s0 = *(const v4f*)&red[0 * 2048 + s];
        v4f s1 = *(const v4f*)&red[1 * 2048 + s];
        v4f s2 = *(const v4f*)&red[2 * 2048 + s];
        v4f s3 = *(const v4f*)&red[3 * 2048 + s];
        *(v4f*)&part[(size_t)hc * 262144 + b * 2048 + s] = (s0 + s1) + (s2 + s3);
    }
}

// sum 8 partials + softmax over S=2048 per batch
__global__ void k_softmax2(const float* __restrict__ part, float* __restrict__ attn) {
    int b = blockIdx.x, t = threadIdx.x;              // block 256
    float v[8];
    float m = -1e30f;
    for (int i = 0; i < 8; ++i) {
        int s = i * 256 + t;
        float acc = 0.f;
        #pragma unroll
        for (int hc = 0; hc < 8; ++hc) acc += part[(size_t)hc * 262144 + b * 2048 + s];
        v[i] = acc; m = fmaxf(m, acc);
    }
    __shared__ float r[256];
    r[t] = m; __syncthreads();
    for (int s = 128; s > 0; s >>= 1) { if (t < s) r[t] = fmaxf(r[t], r[t + s]); __syncthreads(); }
    float M = r[0]; __syncthreads();
    float sum = 0.f;
    for (int i = 0; i < 8; ++i) { v[i] = expf(v[i] - M); sum += v[i]; }
    r[t] = sum; __syncthreads();
    for (int s = 128; s > 0; s >>= 1) { if (t < s) r[t] += r[t + s]; __syncthreads(); }
    float inv = 1.0f / r[0];
    for (int i = 0; i < 8; ++i) attn[b * 2048 + i * 256 + t] = v[i] * inv;
}

// c[b,h] = sum_s attn[b,s]*enc_total[b,h,s]; h_out = glu(y) + c.
// R5 structure (block 256 = 4 waves, attn staged in LDS) + adaptive fp16 cache:
// MODE 0: f32.  MODE 1: f32 read + fp16 nt-store for rows < R.  MODE 2: fp16 read rows < R.
template <int MODE>
__global__ void k_c3(const float* __restrict__ attn, const float* __restrict__ encf,
                     _Float16* __restrict__ e16, const float* __restrict__ y,
                     float* __restrict__ hbuf, int R) {
    int t = threadIdx.x;                              // block 256, grid 16384
    int b  = blockIdx.x >> 7;
    int h0 = (blockIdx.x & 127) << 2;
    __shared__ float al[2048];
    for (int j = t; j < 2048; j += 256) al[j] = attn[b * 2048 + j];
    __syncthreads();
    int w = t >> 6, lane = t & 63;
    int hh = h0 + w;
    int row = b * 512 + hh;
    size_t rowoff = (size_t)row * 2048;
    float acc = 0.f;
    if (MODE == 2 && row < R) {
        #pragma unroll
        for (int it = 0; it < 4; ++it) {
            int s = it * 512 + lane * 8;
            h8 x = __builtin_nontemporal_load((const h8*)(e16 + rowoff + s));
            float4 p0 = *(const float4*)&al[s];
            float4 p1 = *(const float4*)&al[s + 4];
            acc += p0.x * (float)x[0] + p0.y * (float)x[1]
                 + p0.z * (float)x[2] + p0.w * (float)x[3]
                 + p1.x * (float)x[4] + p1.y * (float)x[5]
                 + p1.z * (float)x[6] + p1.w * (float)x[7];
        }
    } else {
        #pragma unroll
        for (int it = 0; it < 8; ++it) {
            int s = it * 256 + lane * 4;
            v4f v = ldnt4(encf + rowoff + s);
            if (MODE == 1 && row < R) {
                h4 x = {(_Float16)v[0], (_Float16)v[1], (_Float16)v[2], (_Float16)v[3]};
                __builtin_nontemporal_store(x, (h4*)(e16 + rowoff + s));
            }
            float4 p = *(const float4*)&al[s];
            acc += p.x * v[0] + p.y * v[1] + p.z * v[2] + p.w * v[3];
        }
    }
    #pragma unroll
    for (int off = 32; off > 0; off >>= 1) acc += __shfl_down(acc, off, 64);
    if (lane == 0) {
        float ya = y[b * 1024 + hh];
        float yb_ = y[b * 1024 + 512 + hh];
        float g = ya / (1.0f + expf(-yb_));
        hbuf[b * 512 + hh] = g + acc;
    }
}

// ---- epilogue (fused logits/log-softmax + softmax over H) ---------------

__global__ void k_epi(const float* __restrict__ h, const float* __restrict__ l2w,
                      const float* __restrict__ l2b, float* __restrict__ out) {
    int b = blockIdx.x, t = threadIdx.x;              // block 256
    __shared__ float hl[512];
    hl[t] = h[b * 512 + t]; hl[t + 256] = h[b * 512 + 256 + t];
    __syncthreads();
    float acc = 0.f;
    if (t < V_) {
        acc = l2b[t];
        for (int e = 0; e < 512; ++e) acc += hl[e] * l2w[t * 512 + e];
    }
    __shared__ float r[256];
    r[t] = (t < V_) ? acc : -1e30f; __syncthreads();
    for (int s = 128; s > 0; s >>= 1) { if (t < s) r[t] = fmaxf(r[t], r[t + s]); __syncthreads(); }
    float M = r[0]; __syncthreads();
    r[t] = (t < V_) ? expf(acc - M) : 0.f; __syncthreads();
    for (int s = 128; s > 0; s >>= 1) { if (t < s) r[t] += r[t + s]; __syncthreads(); }
    float L = M + logf(r[0]);
    if (t < V_) out[65536 + b * V_ + t] = acc - L;
    __syncthreads();
    float v0 = hl[t], v1 = hl[t + 256];
    r[t] = fmaxf(v0, v1); __syncthreads();
    for (int s = 128; s > 0; s >>= 1) { if (t < s) r[t] = fmaxf(r[t], r[t + s]); __syncthreads(); }
    float M2 = r[0]; __syncthreads();
    float e0 = expf(v0 - M2), e1 = expf(v1 - M2);
    r[t] = e0 + e1; __syncthreads();
    for (int s = 128; s > 0; s >>= 1) { if (t < s) r[t] += r[t + s]; __syncthreads(); }
    float inv = 1.0f / r[0];
    out[b * 512 + t] = e0 * inv;
    out[b * 512 + 256 + t] = e1 * inv;
}

// ---- launch --------------------------------------------------------------

extern "C" void kernel_launch(void* const* d_in, const int* in_sizes, int n_in,
                              void* d_out, int out_size, void* d_ws, size_t ws_size,
                              hipStream_t stream) {
    const float* enc_out = (const float*)d_in[0];   // [B,H,S] f32
    const float* enc_tot = (const float*)d_in[1];   // [B,H,S] f32
    const int*   tok     = (const int*)d_in[2];     // [B] int32
    const float* emb     = (const float*)d_in[4];   // [V,E] f32
    const float* conv_w  = (const float*)d_in[5];   // [1024,512,3] f32
    const float* conv_b  = (const float*)d_in[6];   // [1024] f32
    const float* l2w     = (const float*)d_in[7];   // [83,512] f32
    const float* l2b     = (const float*)d_in[8];   // [83] f32
    float* out = (float*)d_out;                     // 65536 + 10624 f32
    float* ws = (float*)d_ws;

    // ws layout (floats)
    float* W2t  = ws;                 // 524288
    float* base = W2t + 524288;       // 1024
    float* pe2  = base + 1024;        // 512
    float* x01i = pe2 + 512;          // 1536
    float* xcol = x01i + 1536;        // 65536
    float* yb   = xcol + 65536;       // 131072
    float* attn = yb + 131072;        // 262144
    float* part = attn + 262144;      // 2097152
    float* hbuf = part + 2097152;     // 65536
    size_t nfloats = 3148800;         // 12.6 MB of live f32 buffers
    _Float16* e16 = (_Float16*)(ws + nfloats);

    // adaptive fp16 enc_tot cache: as many full rows (2048 halfs = 4 KB) as fit
    int R = 0;
    size_t base_bytes = nfloats * 4;
    if (ws_size > base_bytes) {
        size_t rows = (ws_size - base_bytes) / 4096;
        R = (int)(rows > 65536 ? 65536 : rows);
    }

    k_misc<<<1, 512, 0, stream>>>(emb, pe2, x01i);
    k_base3<<<256, 256, 0, stream>>>(conv_w, x01i, base);
    k_prep<<<dim3(16, 4), 256, 0, stream>>>(conv_w, W2t);

    for (int L = 0; L < 3; ++L) {
        k_yx<<<dim3(4, 32), 256, 0, stream>>>(L == 0 ? 1 : 0, tok, emb, hbuf, pe2,
                                              W2t, base, conv_b, xcol, yb);
        k_scores2<<<dim3(8, 128), 256, 0, stream>>>(yb, xcol, enc_out, part);
        k_softmax2<<<128, 256, 0, stream>>>(part, attn);
        if (R == 0)
            k_c3<0><<<16384, 256, 0, stream>>>(attn, enc_tot, e16, yb, hbuf, R);
        else if (L == 0)
            k_c3<1><<<16384, 256, 0, stream>>>(attn, enc_tot, e16, yb, hbuf, R);
        else
            k_c3<2><<<16384, 256, 0, stream>>>(attn, enc_tot, e16, yb, hbuf, R);
    }

    k_epi<<<128, 256, 0, stream>>>(hbuf, l2w, l2b, out);
}

// Round 9
// 583.000 us; speedup vs baseline: 1.4055x; 1.0835x over previous
//
#include <hip/hip_runtime.h>
#include <math.h>

// Problem constants
#define B_   128
#define E_   512
#define H_   512
#define S_   2048
#define V_   83
#define PAD_ 82

typedef float v4f __attribute__((ext_vector_type(4)));

__device__ __forceinline__ v4f ldnt4(const float* p) {
    return __builtin_nontemporal_load((const v4f*)p);
}

// ---- one-time prep -------------------------------------------------------

// pe2[e] = pe(e,2); x01i[e*3+{0,1,2}] = {embPAD[e]+pe(e,0), embPAD[e]+pe(e,1), 0}
__global__ void k_misc(const float* __restrict__ emb, float* __restrict__ pe2,
                       float* __restrict__ x01i) {
    int e = threadIdx.x;                              // 1 block, 512 threads
    float freq = expf(-9.210340371976184f * (float)(e & ~1) * (1.0f / 512.0f));
    float p0 = (e & 1) ? 1.0f : 0.0f;                 // cos(0)/sin(0)
    float p1 = (e & 1) ? cosf(freq) : sinf(freq);
    float p2 = (e & 1) ? cosf(2.0f * freq) : sinf(2.0f * freq);
    pe2[e] = p2;
    float ep = emb[PAD_ * 512 + e];
    x01i[e * 3 + 0] = ep + p0;
    x01i[e * 3 + 1] = ep + p1;
    x01i[e * 3 + 2] = 0.0f;
}

// bc[o] = conv_b[o] + dot(conv_w[o, 0:1536], x01i)  — contiguous rows, wave per o
__global__ void k_base3(const float* __restrict__ cw, const float* __restrict__ x01i,
                        const float* __restrict__ cb, float* __restrict__ bc) {
    int t = threadIdx.x, w = t >> 6, lane = t & 63;   // grid 256, block 256
    __shared__ float xs[1536];
    for (int j = t; j < 1536; j += 256) xs[j] = x01i[j];
    __syncthreads();
    int o = blockIdx.x * 4 + w;
    const float* rp = cw + (size_t)o * 1536 + lane * 4;
    float acc = 0.f;
    #pragma unroll
    for (int j = 0; j < 6; ++j) {
        float4 v = *(const float4*)(rp + j * 256);
        const float* xp = &xs[lane * 4 + j * 256];
        acc += v.x * xp[0] + v.y * xp[1] + v.z * xp[2] + v.w * xp[3];
    }
    #pragma unroll
    for (int off = 32; off > 0; off >>= 1) acc += __shfl_down(acc, off, 64);
    if (lane == 0) bc[o] = acc + cb[o];
}

// Wc[o*512 + e] = conv_w[o*1536 + e*3 + 2]   (compacted k=2 slice, row-major [o][e])
__global__ void k_prepc(const float* __restrict__ cw, float* __restrict__ Wc) {
    int idx = blockIdx.x * 256 + threadIdx.x;        // < 524288
    int o = idx >> 9, e = idx & 511;
    Wc[idx] = cw[o * 1536 + e * 3 + 2];
}

// ---- per-layer kernels ---------------------------------------------------

// Fused x + y + glu/d + partial scores.  grid (16 hc, 128 b), block 256 = 4 waves.
// Block owns 32 h-rows (hg = hc*32 .. +32).  Phase 1: x in LDS.  Phase 2: wave w
// computes rows w*8..w*8+7: ya/yb via 64-lane shuffle dot over Wc rows, glu, d.
// Phase 3: wave w streams ALL 32 enc rows over its own 512-wide s-slice.
__global__ void __launch_bounds__(256) k_syx(
        int first, const int* __restrict__ tok, const float* __restrict__ emb,
        const float* __restrict__ hbuf, const float* __restrict__ pe2,
        const float* __restrict__ Wc, const float* __restrict__ bc,
        const float* __restrict__ eo, float* __restrict__ glu,
        float* __restrict__ part) {
    int hc = blockIdx.x, b = blockIdx.y, t = threadIdx.x;
    int w = t >> 6, lane = t & 63;
    __shared__ float xs[512];
    __shared__ float dl[32];
    for (int e = t; e < 512; e += 256) {
        float v = first ? emb[tok[b] * 512 + e] : hbuf[b * 512 + e];
        xs[e] = v + pe2[e];
    }
    __syncthreads();
    // Phase 2: y-pairs for this wave's 8 rows
    for (int r = 0; r < 8; ++r) {
        int hg = hc * 32 + w * 8 + r;
        const float* wa = Wc + (size_t)hg * 512;
        const float* wb = Wc + (size_t)(512 + hg) * 512;
        float pa = 0.f, pb = 0.f;
        #pragma unroll
        for (int k = 0; k < 8; ++k) {
            int e = lane + k * 64;
            float x = xs[e];
            pa += wa[e] * x;
            pb += wb[e] * x;
        }
        #pragma unroll
        for (int off = 32; off > 0; off >>= 1) {
            pa += __shfl_xor(pa, off, 64);
            pb += __shfl_xor(pb, off, 64);
        }
        if (lane == 0) {
            float ya = pa + bc[hg];
            float yb = pb + bc[512 + hg];
            float g = ya / (1.0f + expf(-yb));
            glu[b * 512 + hg] = g;
            dl[w * 8 + r] = g + xs[hg];
        }
    }
    __syncthreads();
    // Phase 3: stream 32 rows, wave-private s-slice [w*512, w*512+512)
    v4f a0 = (v4f)(0.f), a1 = (v4f)(0.f);
    const float* bp = eo + ((size_t)b * 512 + hc * 32) * 2048 + w * 512 + lane * 4;
    for (int r = 0; r < 32; ++r) {
        float dh = dl[r];
        const float* rp = bp + (size_t)r * 2048;
        a0 += dh * ldnt4(rp);
        a1 += dh * ldnt4(rp + 256);
    }
    float* pp = part + (size_t)hc * 262144 + b * 2048 + w * 512 + lane * 4;
    *(v4f*)pp = a0;
    *(v4f*)(pp + 256) = a1;
}

// sum 16 partials + softmax over S=2048 per batch; block 256, v4f slots
__global__ void k_softmax2(const float* __restrict__ part, float* __restrict__ attn) {
    int b = blockIdx.x, t = threadIdx.x;              // block 256
    v4f v0 = (v4f)(0.f), v1 = (v4f)(0.f);
    #pragma unroll
    for (int hc = 0; hc < 16; ++hc) {
        const float* pp = part + (size_t)hc * 262144 + b * 2048 + t * 4;
        v0 += *(const v4f*)pp;
        v1 += *(const v4f*)(pp + 1024);
    }
    float m = fmaxf(fmaxf(fmaxf(v0[0], v0[1]), fmaxf(v0[2], v0[3])),
                    fmaxf(fmaxf(v1[0], v1[1]), fmaxf(v1[2], v1[3])));
    __shared__ float r[256];
    r[t] = m; __syncthreads();
    for (int s = 128; s > 0; s >>= 1) { if (t < s) r[t] = fmaxf(r[t], r[t + s]); __syncthreads(); }
    float M = r[0]; __syncthreads();
    v4f e0, e1;
    float sum = 0.f;
    #pragma unroll
    for (int i = 0; i < 4; ++i) { e0[i] = expf(v0[i] - M); sum += e0[i]; }
    #pragma unroll
    for (int i = 0; i < 4; ++i) { e1[i] = expf(v1[i] - M); sum += e1[i]; }
    r[t] = sum; __syncthreads();
    for (int s = 128; s > 0; s >>= 1) { if (t < s) r[t] += r[t + s]; __syncthreads(); }
    float inv = 1.0f / r[0];
    *(v4f*)&attn[b * 2048 + t * 4] = e0 * inv;
    *(v4f*)&attn[b * 2048 + 1024 + t * 4] = e1 * inv;
}

// c[b,h] = sum_s attn[b,s]*enc_total[b,h,s]; h_out = glu + c.
// block 256 = 4 waves, one h-row each; attn staged in LDS; nt enc stream.
__global__ void k_c2(const float* __restrict__ attn, const float* __restrict__ enc,
                     const float* __restrict__ glu, float* __restrict__ hbuf) {
    int t = threadIdx.x;                              // block 256, grid 16384
    int b  = blockIdx.x >> 7;
    int h0 = (blockIdx.x & 127) << 2;
    __shared__ float al[2048];
    for (int j = t; j < 2048; j += 256) al[j] = attn[b * 2048 + j];
    __syncthreads();
    int w = t >> 6, lane = t & 63;
    int hh = h0 + w;
    const float* vp = enc + ((size_t)b * 512 + hh) * 2048;
    float acc = 0.f;
    #pragma unroll
    for (int it = 0; it < 8; ++it) {
        int s = it * 256 + lane * 4;
        v4f v = ldnt4(vp + s);
        float4 p = *(const float4*)&al[s];
        acc += p.x * v[0] + p.y * v[1] + p.z * v[2] + p.w * v[3];
    }
    #pragma unroll
    for (int off = 32; off > 0; off >>= 1) acc += __shfl_down(acc, off, 64);
    if (lane == 0) hbuf[b * 512 + hh] = glu[b * 512 + hh] + acc;
}

// ---- epilogue (fused logits/log-softmax + softmax over H) ---------------

__global__ void k_epi(const float* __restrict__ h, const float* __restrict__ l2w,
                      const float* __restrict__ l2b, float* __restrict__ out) {
    int b = blockIdx.x, t = threadIdx.x;              // block 256
    __shared__ float hl[512];
    hl[t] = h[b * 512 + t]; hl[t + 256] = h[b * 512 + 256 + t];
    __syncthreads();
    float acc = 0.f;
    if (t < V_) {
        acc = l2b[t];
        for (int e = 0; e < 512; ++e) acc += hl[e] * l2w[t * 512 + e];
    }
    __shared__ float r[256];
    r[t] = (t < V_) ? acc : -1e30f; __syncthreads();
    for (int s = 128; s > 0; s >>= 1) { if (t < s) r[t] = fmaxf(r[t], r[t + s]); __syncthreads(); }
    float M = r[0]; __syncthreads();
    r[t] = (t < V_) ? expf(acc - M) : 0.f; __syncthreads();
    for (int s = 128; s > 0; s >>= 1) { if (t < s) r[t] += r[t + s]; __syncthreads(); }
    float L = M + logf(r[0]);
    if (t < V_) out[65536 + b * V_ + t] = acc - L;
    __syncthreads();
    float v0 = hl[t], v1 = hl[t + 256];
    r[t] = fmaxf(v0, v1); __syncthreads();
    for (int s = 128; s > 0; s >>= 1) { if (t < s) r[t] = fmaxf(r[t], r[t + s]); __syncthreads(); }
    float M2 = r[0]; __syncthreads();
    float e0 = expf(v0 - M2), e1 = expf(v1 - M2);
    r[t] = e0 + e1; __syncthreads();
    for (int s = 128; s > 0; s >>= 1) { if (t < s) r[t] += r[t + s]; __syncthreads(); }
    float inv = 1.0f / r[0];
    out[b * 512 + t] = e0 * inv;
    out[b * 512 + 256 + t] = e1 * inv;
}

// ---- launch --------------------------------------------------------------

extern "C" void kernel_launch(void* const* d_in, const int* in_sizes, int n_in,
                              void* d_out, int out_size, void* d_ws, size_t ws_size,
                              hipStream_t stream) {
    const float* enc_out = (const float*)d_in[0];   // [B,H,S] f32
    const float* enc_tot = (const float*)d_in[1];   // [B,H,S] f32
    const int*   tok     = (const int*)d_in[2];     // [B] int32
    const float* emb     = (const float*)d_in[4];   // [V,E] f32
    const float* conv_w  = (const float*)d_in[5];   // [1024,512,3] f32
    const float* conv_b  = (const float*)d_in[6];   // [1024] f32
    const float* l2w     = (const float*)d_in[7];   // [83,512] f32
    const float* l2b     = (const float*)d_in[8];   // [83] f32
    float* out = (float*)d_out;                     // 65536 + 10624 f32
    float* ws = (float*)d_ws;

    // ws layout (floats)
    float* Wc   = ws;                 // 524288  ([o][e] compact k=2 slice)
    float* bc   = Wc + 524288;        // 1024    (base + conv_b)
    float* pe2  = bc + 1024;          // 512
    float* x01i = pe2 + 512;          // 1536
    float* glu  = x01i + 1536;        // 65536
    float* part = glu + 65536;        // 16*262144 = 4194304
    float* attn = part + 4194304;     // 262144
    float* hbuf = attn + 262144;      // 65536
    // total ~20.5 MB

    k_misc<<<1, 512, 0, stream>>>(emb, pe2, x01i);
    k_base3<<<256, 256, 0, stream>>>(conv_w, x01i, conv_b, bc);
    k_prepc<<<2048, 256, 0, stream>>>(conv_w, Wc);

    for (int L = 0; L < 3; ++L) {
        k_syx<<<dim3(16, 128), 256, 0, stream>>>(L == 0 ? 1 : 0, tok, emb, hbuf, pe2,
                                                 Wc, bc, enc_out, glu, part);
        k_softmax2<<<128, 256, 0, stream>>>(part, attn);
        k_c2<<<16384, 256, 0, stream>>>(attn, enc_tot, glu, hbuf);
    }

    k_epi<<<128, 256, 0, stream>>>(hbuf, l2w, l2b, out);
}